// Round 6
// baseline (29.968 us; speedup 1.0000x reference)
//
#include <hip/hip_runtime.h>

// PSANet COLLECT forward, N=1, H=W=60.
//   out[oh*60+ow][h][w] = x[(oh+59-h)*119 + (ow+59-w)][h][w]
//
// One WG per (oh, h-pair) -- 1800 WGs, 512 threads. Trimmed-parallelogram
// reads, compact LDS scatter lds[hh][ow*60+w] (ow = b+w-59), float4
// contiguous 480 B stores per output channel.
//
// R6 changes vs R5:
//  - 2D-tiled XCD swizzle: 8 chunks of 15 oh x 15 hp (row-major in oh).
//    Read-boundary partner (oh+1,hp) at distance 15, write partner
//    (oh,hp+-1) at distance 1 -> both L2-captured.
//  - Nontemporal stores (write-once data, keep L2 for read reuse).

#define CH_STRIDE 3600   // H*W floats per channel

typedef float f32x4 __attribute__((ext_vector_type(4)));

__global__ __launch_bounds__(512) void psa_collect_kernel(
    const float* __restrict__ x, float* __restrict__ out) {

    __shared__ float lds[2][3600];    // 28.8 KB, compact parallelogram

    // 2D-tiled XCD swizzle: 1800 = 8 XCD-chunks x (15 oh x 15 hp).
    const int xcd = blockIdx.x & 7;          // dispatch round-robins XCDs
    const int t   = blockIdx.x >> 3;         // [0,225) within chunk
    const int ti  = t / 15;                  // oh within chunk
    const int tj  = t - ti * 15;             // hp within chunk
    const int oh  = (xcd >> 1) * 15 + ti;    // [0,60)
    const int hp  = (xcd & 1) * 15 + tj;     // [0,30)
    const int h0  = hp * 2;
    const int tid = threadIdx.x;

    // ---- Phase 1: global -> compact LDS (trimmed parallelogram) ----
    for (int hh = 0; hh < 2; ++hh) {
        const int h = h0 + hh;
        const int a = oh + 59 - h;                  // channel-grid row
        const float* src = x + (size_t)a * 119 * CH_STRIDE + h * 60;
        for (int tt = tid; tt < 119 * 15; tt += 512) {
            const int b  = tt / 15;                 // channel-grid col
            const int j4 = (tt - b * 15) * 4;       // first w of this float4
            const int w0 = (b < 59) ? (59 - b) : 0;
            const int w1 = (b < 59) ? 60 : (119 - b);
            if (j4 < w1 && j4 + 4 > w0) {
                const float4 v =
                    *reinterpret_cast<const float4*>(src + (size_t)b * CH_STRIDE + j4);
                const float* ve = reinterpret_cast<const float*>(&v);
#pragma unroll
                for (int e = 0; e < 4; ++e) {
                    const int w = j4 + e;
                    const int d = b + w - 59;       // = ow, in [0,60) iff used
                    if ((unsigned)d < 60u) lds[hh][d * 60 + w] = ve[e];
                }
            }
        }
    }
    __syncthreads();

    // ---- Phase 2: LDS -> global, 480 B contiguous per output channel ----
    float* dst = out + (size_t)(oh * 60) * CH_STRIDE + h0 * 60;
    for (int m = tid; m < 1800; m += 512) {
        const int ow = m / 30;
        const int r  = m - ow * 30;                 // 0..29: (hh, j4)
        const int hh = r / 15;
        const int j4 = (r - hh * 15) * 4;
        const f32x4 v = *reinterpret_cast<const f32x4*>(&lds[hh][ow * 60 + j4]);
        __builtin_nontemporal_store(
            v, reinterpret_cast<f32x4*>(dst + (size_t)ow * CH_STRIDE + hh * 60 + j4));
    }
}

extern "C" void kernel_launch(void* const* d_in, const int* in_sizes, int n_in,
                              void* d_out, int out_size, void* d_ws, size_t ws_size,
                              hipStream_t stream) {
    const float* x = (const float*)d_in[0];
    float* out = (float*)d_out;
    // 1800 workgroups of 512 threads: one per (oh, h-pair).
    psa_collect_kernel<<<dim3(1800), dim3(512), 0, stream>>>(x, out);
}